// Round 3
// baseline (245.913 us; speedup 1.0000x reference)
//
#include <hip/hip_runtime.h>

// EMA recurrence: s_t = alpha*s_{t-1} + (1-alpha)*x_t
// x: (T=1024, 32, 1024) fp32, state: (32, 1024) fp32
// out = concat(all states (T,32,1024), final_state (32,1024))
//
// R2: R1 crashed — CHUNK=64 < WARM=96 gave chunk 1 a negative warm-up start
// (OOB read of x, GPU page fault). Fix: clamp warm start to 0, and when the
// warm window reaches t=0 seed with `state` (chunks 0 and 1 become EXACT).
// Chunks >=2 splice with alpha^96 ~ 4e-5 error (|s|~0.23 -> ~1e-5 abs).
//
// Structure (R1 theory, still untested): 16 time-chunks x 16384 float2 lanes
// = 1024 blocks (4/CU), float2 loads/stores for 2 independent FMA chains,
// nontemporal stores so write-once `out` doesn't evict x from L2/L3 (warm-up
// re-reads then hit cache).

typedef float floatv __attribute__((ext_vector_type(2)));

constexpr int T = 1024;
constexpr int C = 32 * 1024;       // channels per timestep (contiguous)
constexpr int VEC = 2;
constexpr int CV = C / VEC;        // 16384 float2 channels
constexpr int CHUNK = 64;          // timesteps per chunk
constexpr int NCHUNK = T / CHUNK;  // 16
constexpr int WARM = 96;           // warm-up steps (clamped at t=0)

__global__ __launch_bounds__(256)
void ExponentialDecay_23708219474744_kernel(const float* __restrict__ x,
                                            const float* __restrict__ state,
                                            float* __restrict__ out) {
    const int cv = blockIdx.x * blockDim.x + threadIdx.x;   // 0..CV-1, coalesced
    const int chunk = blockIdx.y;
    const int t0 = chunk * CHUNK;

    const float a = 0.9f;
    const float oma = 0.1f;

    const floatv* xv = (const floatv*)x;
    floatv* outv = (floatv*)out;

    int tw = t0 - WARM;
    floatv s;
    if (tw <= 0) {
        tw = 0;
        s = ((const floatv*)state)[cv];   // exact initial state
    } else {
        s = (floatv)(0.0f);               // alpha^WARM splice error
    }

    // warm-up: recurrence only, no stores (empty for chunk 0)
    #pragma unroll 8
    for (int t = tw; t < t0; ++t) {
        floatv v = xv[(size_t)t * CV + cv];
        s = s * a + v * oma;
    }

    const int t1 = t0 + CHUNK;
    #pragma unroll 8
    for (int t = t0; t < t1; ++t) {
        floatv v = xv[(size_t)t * CV + cv];
        s = s * a + v * oma;
        __builtin_nontemporal_store(s, &outv[(size_t)t * CV + cv]);
    }

    if (chunk == NCHUNK - 1) {
        // final_state, appended after the (T,32,1024) outputs
        outv[(size_t)T * CV + cv] = s;
    }
}

extern "C" void kernel_launch(void* const* d_in, const int* in_sizes, int n_in,
                              void* d_out, int out_size, void* d_ws, size_t ws_size,
                              hipStream_t stream) {
    const float* x = (const float*)d_in[0];
    const float* state = (const float*)d_in[1];
    float* out = (float*)d_out;

    dim3 block(256);
    dim3 grid(CV / 256, NCHUNK);   // 64 x 16 = 1024 blocks = 4 per CU
    ExponentialDecay_23708219474744_kernel<<<grid, block, 0, stream>>>(x, state, out);
}